// Round 1
// baseline (833.916 us; speedup 1.0000x reference)
//
#include <hip/hip_runtime.h>

#define NN 100000            // nodes
#define NE 1200000           // edges
#define NRR 400000           // N*R
#define SEGF 25600000        // N*R*64 floats

typedef float f32x4 __attribute__((ext_vector_type(4)));
typedef __bf16 bf16x8 __attribute__((ext_vector_type(8)));

__device__ __forceinline__ float sigmoidf_(float x){ return 1.0f/(1.0f+__expf(-x)); }

// pack 8 fp32 -> 8 bf16 (truncate) via v_perm_b32, 1 instr per pair
__device__ __forceinline__ bf16x8 pack_bf16x8(f32x4 a, f32x4 b){
  union { unsigned u[4]; bf16x8 v; } o;
  o.u[0] = __builtin_amdgcn_perm(__float_as_uint(a[1]), __float_as_uint(a[0]), 0x07060302u);
  o.u[1] = __builtin_amdgcn_perm(__float_as_uint(a[3]), __float_as_uint(a[2]), 0x07060302u);
  o.u[2] = __builtin_amdgcn_perm(__float_as_uint(b[1]), __float_as_uint(b[0]), 0x07060302u);
  o.u[3] = __builtin_amdgcn_perm(__float_as_uint(b[3]), __float_as_uint(b[2]), 0x07060302u);
  return o.v;
}

__global__ void count_kernel(const int* __restrict__ dst, const int* __restrict__ rel,
                             int* __restrict__ cnt){
  int i = blockIdx.x*256 + threadIdx.x;
  if (i < NE) atomicAdd(&cnt[dst[i]*4 + rel[i]], 1);
}

__global__ void inv_kernel(const int* __restrict__ cnt, float* __restrict__ inv){
  int i = blockIdx.x*256 + threadIdx.x;
  if (i < NRR) inv[i] = 1.0f / fmaxf((float)cnt[i], 1.0f);
}

// build bf16 weights: W1=[w|ws] (64 x 320), W2=[pw;tw] (128 x 128), bias1=b+bs, bias2=[pb|tb]
__global__ void prep_kernel(const float* __restrict__ w,  const float* __restrict__ b,
                            const float* __restrict__ ws, const float* __restrict__ bs,
                            const float* __restrict__ pw, const float* __restrict__ pb,
                            const float* __restrict__ tw, const float* __restrict__ tb,
                            __bf16* __restrict__ W1, __bf16* __restrict__ W2,
                            float* __restrict__ bias1, float* __restrict__ bias2){
  int i = blockIdx.x*256 + threadIdx.x;
  if (i < 64*320) {
    int n = i/320, k = i - n*320;
    float v = (k < 256) ? w[n*256+k] : ws[n*64 + (k-256)];
    W1[i] = (__bf16)v;
  }
  if (i < 128*128) {
    int n = i >> 7, k = i & 127;
    float v = (n < 64) ? pw[n*128+k] : tw[(n-64)*128+k];
    W2[i] = (__bf16)v;
  }
  if (i < 64)  bias1[i] = b[i] + bs[i];
  if (i < 128) bias2[i] = (i < 64) ? pb[i] : tb[i-64];
}

// one wave per edge (lane = feature), contributions pre-scaled by inv[dst*4+rel]
__global__ void scatter_kernel(const float* __restrict__ x, const int* __restrict__ src,
                               const int* __restrict__ dst, const int* __restrict__ rel,
                               const float* __restrict__ inv, float* __restrict__ seg){
  int e = blockIdx.x*4 + (threadIdx.x >> 6);
  if (e >= NE) return;
  int lane = threadIdx.x & 63;
  int s = src[e];
  int t = dst[e]*4 + rel[e];
  float v = x[(size_t)s*64 + lane] * inv[t];
  unsafeAtomicAdd(&seg[(size_t)t*64 + lane], v);
}

// Fused conv-dense + highway. Block = 128 nodes (two 64-row halves), 4 waves.
// GEMM1: [128 x 320] @ W1^T -> sigmoid -> h ; GEMM2: [h|prev] @ W2^T -> highway.
#define W2P 136   // LDS pitch (bf16) for W2, 16B-aligned rows
#define HSP 72    // LDS pitch (bf16) for h staging

template<bool WRITE_H>
__global__ __launch_bounds__(256)
void dense_kernel(const float* __restrict__ seg,   // [N*R*64] pre-scaled sums = upd
                  const float* __restrict__ xin,   // [N,64] conv self input
                  const float* __restrict__ prev,  // [N,64] highway prev
                  const __bf16* __restrict__ W1,   // [64][320]
                  const __bf16* __restrict__ W2,   // [128][128]
                  const float* __restrict__ bias1, // [64]
                  const float* __restrict__ bias2, // [128]
                  float* __restrict__ hout,        // [N,64]
                  float* __restrict__ outp)        // [N,64]
{
  __shared__ __bf16 w2s[128*W2P];
  __shared__ __bf16 hs[128*HSP];

  const int tid = threadIdx.x;
  // stage W2 into LDS (16KB of bf16 data)
  #pragma unroll
  for (int i = 0; i < 8; ++i) {
    int idx = i*2048 + tid*8;
    int n = idx >> 7, k = idx & 127;
    *(bf16x8*)(&w2s[n*W2P + k]) = *(const bf16x8*)(&W2[idx]);
  }
  __syncthreads();

  const int lane = tid & 63;
  const int wv   = tid >> 6;
  const int mloc = lane & 15;   // A-row / B-col within 16-tile
  const int kg   = lane >> 4;   // k-group
  const int base = blockIdx.x * 128;

  int arow[2];
  arow[0] = min(base      + wv*16 + mloc, NN-1);
  arow[1] = min(base + 64 + wv*16 + mloc, NN-1);

  f32x4 acc1[2][4] = {};

  // GEMM1 part 1: K = 0..256 from seg (upd)
  #pragma unroll
  for (int kb = 0; kb < 256; kb += 32) {
    bf16x8 bf[4];
    #pragma unroll
    for (int j = 0; j < 4; ++j)
      bf[j] = *(const bf16x8*)(&W1[(j*16 + mloc)*320 + kb + kg*8]);
    #pragma unroll
    for (int h = 0; h < 2; ++h) {
      const float* ap = seg + (size_t)arow[h]*256 + kb + kg*8;
      f32x4 a0 = *(const f32x4*)ap;
      f32x4 a1 = *(const f32x4*)(ap+4);
      bf16x8 af = pack_bf16x8(a0, a1);
      #pragma unroll
      for (int j = 0; j < 4; ++j)
        acc1[h][j] = __builtin_amdgcn_mfma_f32_16x16x32_bf16(af, bf[j], acc1[h][j], 0,0,0);
    }
  }
  // GEMM1 part 2: K = 256..320 from xin (self loop)
  #pragma unroll
  for (int kb = 0; kb < 64; kb += 32) {
    bf16x8 bf[4];
    #pragma unroll
    for (int j = 0; j < 4; ++j)
      bf[j] = *(const bf16x8*)(&W1[(j*16 + mloc)*320 + 256 + kb + kg*8]);
    #pragma unroll
    for (int h = 0; h < 2; ++h) {
      const float* ap = xin + (size_t)arow[h]*64 + kb + kg*8;
      f32x4 a0 = *(const f32x4*)ap;
      f32x4 a1 = *(const f32x4*)(ap+4);
      bf16x8 af = pack_bf16x8(a0, a1);
      #pragma unroll
      for (int j = 0; j < 4; ++j)
        acc1[h][j] = __builtin_amdgcn_mfma_f32_16x16x32_bf16(af, bf[j], acc1[h][j], 0,0,0);
    }
  }

  // epilogue 1: h = sigmoid(acc + bias1); keep in regs, stage bf16 in LDS, optionally write
  #pragma unroll
  for (int h = 0; h < 2; ++h) {
    #pragma unroll
    for (int j = 0; j < 4; ++j) {
      int col = j*16 + mloc;
      float b1 = bias1[col];
      #pragma unroll
      for (int r = 0; r < 4; ++r) {
        float hv = sigmoidf_(acc1[h][j][r] + b1);
        acc1[h][j][r] = hv;
        int trow = h*64 + wv*16 + kg*4 + r;
        hs[trow*HSP + col] = (__bf16)hv;
        int grow = base + trow;
        if (WRITE_H && grow < NN) hout[(size_t)grow*64 + col] = hv;
      }
    }
  }
  // hs rows are wave-private (same wave writes & reads its 16-node rows) -> no barrier needed

  f32x4 acc2[2][8] = {};
  // GEMM2 part 1: K = 0..64 -> c = h (from LDS)
  #pragma unroll
  for (int kb = 0; kb < 64; kb += 32) {
    bf16x8 af[2];
    #pragma unroll
    for (int h = 0; h < 2; ++h) {
      int trow = h*64 + wv*16 + mloc;
      af[h] = *(const bf16x8*)(&hs[trow*HSP + kb + kg*8]);
    }
    #pragma unroll
    for (int j = 0; j < 8; ++j) {
      bf16x8 bf = *(const bf16x8*)(&w2s[(j*16 + mloc)*W2P + kb + kg*8]);
      #pragma unroll
      for (int h = 0; h < 2; ++h)
        acc2[h][j] = __builtin_amdgcn_mfma_f32_16x16x32_bf16(af[h], bf, acc2[h][j], 0,0,0);
    }
  }
  // GEMM2 part 2: K = 64..128 -> c = prev (global fp32)
  #pragma unroll
  for (int kb = 0; kb < 64; kb += 32) {
    bf16x8 af[2];
    #pragma unroll
    for (int h = 0; h < 2; ++h) {
      const float* pp = prev + (size_t)arow[h]*64 + kb + kg*8;
      f32x4 a0 = *(const f32x4*)pp;
      f32x4 a1 = *(const f32x4*)(pp+4);
      af[h] = pack_bf16x8(a0, a1);
    }
    #pragma unroll
    for (int j = 0; j < 8; ++j) {
      bf16x8 bf = *(const bf16x8*)(&w2s[(j*16 + mloc)*W2P + 64 + kb + kg*8]);
      #pragma unroll
      for (int h = 0; h < 2; ++h)
        acc2[h][j] = __builtin_amdgcn_mfma_f32_16x16x32_bf16(af[h], bf, acc2[h][j], 0,0,0);
    }
  }

  // epilogue 2: pr = relu(.+pb), g = sigmoid(.+tb), out = g*pr + (1-g)*h
  #pragma unroll
  for (int h = 0; h < 2; ++h) {
    #pragma unroll
    for (int j = 0; j < 4; ++j) {
      int col = j*16 + mloc;
      float bp = bias2[col];
      float bt = bias2[64 + col];
      #pragma unroll
      for (int r = 0; r < 4; ++r) {
        float pr = fmaxf(acc2[h][j][r] + bp, 0.0f);
        float g  = sigmoidf_(acc2[h][j+4][r] + bt);
        float hv = acc1[h][j][r];
        float ov = g*pr + (1.0f - g)*hv;
        int grow = base + h*64 + wv*16 + kg*4 + r;
        if (grow < NN) outp[(size_t)grow*64 + col] = ov;
      }
    }
  }
}

extern "C" void kernel_launch(void* const* d_in, const int* in_sizes, int n_in,
                              void* d_out, int out_size, void* d_ws, size_t ws_size,
                              hipStream_t stream){
  const float* x    = (const float*)d_in[0];
  const int*   src  = (const int*)d_in[1];
  const int*   dst  = (const int*)d_in[2];
  const int*   rel  = (const int*)d_in[3];
  const float* c1w  = (const float*)d_in[4];
  const float* c1b  = (const float*)d_in[5];
  const float* c1ws = (const float*)d_in[6];
  const float* c1bs = (const float*)d_in[7];
  const float* h1pw = (const float*)d_in[8];
  const float* h1pb = (const float*)d_in[9];
  const float* h1tw = (const float*)d_in[10];
  const float* h1tb = (const float*)d_in[11];
  const float* c2w  = (const float*)d_in[12];
  const float* c2b  = (const float*)d_in[13];
  const float* c2ws = (const float*)d_in[14];
  const float* c2bs = (const float*)d_in[15];
  const float* h2pw = (const float*)d_in[16];
  const float* h2pb = (const float*)d_in[17];
  const float* h2tw = (const float*)d_in[18];
  const float* h2tb = (const float*)d_in[19];

  char* p = (char*)d_ws;
  float* seg = (float*)p;          p += (size_t)SEGF*4;
  int*   cnt = (int*)p;            p += (size_t)NRR*4;
  float* inv = (float*)p;          p += (size_t)NRR*4;
  float* h1  = (float*)p;          p += (size_t)NN*64*4;
  float* g1  = (float*)p;          p += (size_t)NN*64*4;
  __bf16* W1a = (__bf16*)p;        p += 64*320*2;
  __bf16* W2a = (__bf16*)p;        p += 128*128*2;
  __bf16* W1b = (__bf16*)p;        p += 64*320*2;
  __bf16* W2b = (__bf16*)p;        p += 128*128*2;
  float* B1a = (float*)p;          p += 64*4;
  float* B2a = (float*)p;          p += 128*4;
  float* B1b = (float*)p;          p += 64*4;
  float* B2b = (float*)p;          p += 128*4;

  float* out = (float*)d_out;

  hipMemsetAsync(cnt, 0, (size_t)NRR*4, stream);
  count_kernel<<<(NE+255)/256, 256, 0, stream>>>(dst, rel, cnt);
  inv_kernel<<<(NRR+255)/256, 256, 0, stream>>>(cnt, inv);
  prep_kernel<<<80, 256, 0, stream>>>(c1w, c1b, c1ws, c1bs, h1pw, h1pb, h1tw, h1tb,
                                      W1a, W2a, B1a, B2a);
  prep_kernel<<<80, 256, 0, stream>>>(c2w, c2b, c2ws, c2bs, h2pw, h2pb, h2tw, h2tb,
                                      W1b, W2b, B1b, B2b);

  // layer 1
  hipMemsetAsync(seg, 0, (size_t)SEGF*4, stream);
  scatter_kernel<<<(NE+3)/4, 256, 0, stream>>>(x, src, dst, rel, inv, seg);
  dense_kernel<true><<<(NN+127)/128, 256, 0, stream>>>(seg, x, x, W1a, W2a, B1a, B2a, h1, g1);

  // layer 2
  hipMemsetAsync(seg, 0, (size_t)SEGF*4, stream);
  scatter_kernel<<<(NE+3)/4, 256, 0, stream>>>(g1, src, dst, rel, inv, seg);
  dense_kernel<false><<<(NN+127)/128, 256, 0, stream>>>(seg, g1, h1, W1b, W2b, B1b, B2b, h1, out);
}

// Round 2
// 489.303 us; speedup vs baseline: 1.7043x; 1.7043x over previous
//
#include <hip/hip_runtime.h>

#define NN 100000            // nodes
#define NE 1200000           // edges
#define NRR 400000           // N*R segments
#define NB 98                // scan blocks: ceil(NRR/4096)

typedef float f32x4 __attribute__((ext_vector_type(4)));
typedef __bf16 bf16x4 __attribute__((ext_vector_type(4)));
typedef __bf16 bf16x8 __attribute__((ext_vector_type(8)));

__device__ __forceinline__ float sigmoidf_(float x){ return 1.0f/(1.0f+__expf(-x)); }

// ---------------- CSR build ----------------

__global__ void count_kernel(const int* __restrict__ dst, const int* __restrict__ rel,
                             int* __restrict__ cnt){
  int i = blockIdx.x*256 + threadIdx.x;
  if (i < NE) atomicAdd(&cnt[dst[i]*4 + rel[i]], 1);
}

__global__ void scan1_kernel(const int* __restrict__ cnt, int* __restrict__ bsum){
  __shared__ int ws[4];
  int b = blockIdx.x, t = threadIdx.x;
  int base = b*4096 + t*16;
  int s = 0;
  #pragma unroll
  for (int i = 0; i < 16; ++i){ int idx = base + i; s += (idx < NRR) ? cnt[idx] : 0; }
  #pragma unroll
  for (int off = 32; off; off >>= 1) s += __shfl_down(s, off);
  if ((t & 63) == 0) ws[t >> 6] = s;
  __syncthreads();
  if (t == 0) bsum[b] = ws[0] + ws[1] + ws[2] + ws[3];
}

__global__ void scan2_kernel(const int* __restrict__ bsum, int* __restrict__ bbase){
  __shared__ int buf[128];
  int t = threadIdx.x;
  buf[t] = (t < NB) ? bsum[t] : 0;
  __syncthreads();
  for (int off = 1; off < 128; off <<= 1){
    int v = buf[t];
    int u = (t >= off) ? buf[t-off] : 0;
    __syncthreads();
    buf[t] = v + u;
    __syncthreads();
  }
  if (t < NB) bbase[t] = (t == 0) ? 0 : buf[t-1];
}

__global__ void scan3_kernel(const int* __restrict__ cnt, const int* __restrict__ bbase,
                             int* __restrict__ off, int* __restrict__ cursor){
  __shared__ int tsum[256];
  int b = blockIdx.x, t = threadIdx.x;
  int base = b*4096 + t*16;
  int loc[16]; int s = 0;
  #pragma unroll
  for (int i = 0; i < 16; ++i){
    int idx = base + i;
    int c = (idx < NRR) ? cnt[idx] : 0;
    loc[i] = s; s += c;
  }
  tsum[t] = s;
  __syncthreads();
  for (int o = 1; o < 256; o <<= 1){
    int v = tsum[t];
    int u = (t >= o) ? tsum[t-o] : 0;
    __syncthreads();
    tsum[t] = v + u;
    __syncthreads();
  }
  int tbase = bbase[b] + ((t == 0) ? 0 : tsum[t-1]);
  #pragma unroll
  for (int i = 0; i < 16; ++i){
    int idx = base + i;
    if (idx < NRR){ int o = tbase + loc[i]; off[idx] = o; cursor[idx] = o; }
  }
}

__global__ void place_kernel(const int* __restrict__ src, const int* __restrict__ dst,
                             const int* __restrict__ rel, int* __restrict__ cursor,
                             int* __restrict__ elist){
  int e = blockIdx.x*256 + threadIdx.x;
  if (e < NE){
    int s = dst[e]*4 + rel[e];
    int p = atomicAdd(&cursor[s], 1);
    elist[p] = src[e];
  }
}

// ---------------- conversions / weight prep ----------------

__global__ void tobf16_kernel(const float* __restrict__ xf, __bf16* __restrict__ xb){
  int i = (blockIdx.x*256 + threadIdx.x)*8;
  if (i < NN*64){
    f32x4 a = *(const f32x4*)(xf + i);
    f32x4 b = *(const f32x4*)(xf + i + 4);
    bf16x8 r;
    r[0]=(__bf16)a[0]; r[1]=(__bf16)a[1]; r[2]=(__bf16)a[2]; r[3]=(__bf16)a[3];
    r[4]=(__bf16)b[0]; r[5]=(__bf16)b[1]; r[6]=(__bf16)b[2]; r[7]=(__bf16)b[3];
    *(bf16x8*)(xb + i) = r;
  }
}

// W1=[w|ws] (64 x 320), W2=[pw;tw] (128 x 128), bias1=b+bs, bias2=[pb|tb]
__global__ void prep_kernel(const float* __restrict__ w,  const float* __restrict__ b,
                            const float* __restrict__ ws, const float* __restrict__ bs,
                            const float* __restrict__ pw, const float* __restrict__ pb,
                            const float* __restrict__ tw, const float* __restrict__ tb,
                            __bf16* __restrict__ W1, __bf16* __restrict__ W2,
                            float* __restrict__ bias1, float* __restrict__ bias2){
  int i = blockIdx.x*256 + threadIdx.x;
  if (i < 64*320) {
    int n = i/320, k = i - n*320;
    float v = (k < 256) ? w[n*256+k] : ws[n*64 + (k-256)];
    W1[i] = (__bf16)v;
  }
  if (i < 128*128) {
    int n = i >> 7, k = i & 127;
    float v = (n < 64) ? pw[n*128+k] : tw[(n-64)*128+k];
    W2[i] = (__bf16)v;
  }
  if (i < 64)  bias1[i] = b[i] + bs[i];
  if (i < 128) bias2[i] = (i < 64) ? pb[i] : tb[i-64];
}

// ---------------- gather-mean (CSR) ----------------
// 16 lanes per segment (lane covers 4 features via bf16x4), 16 segments/block.
__global__ __launch_bounds__(256)
void gather_kernel(const __bf16* __restrict__ xb, const int* __restrict__ elist,
                   const int* __restrict__ off, const int* __restrict__ cnt,
                   __bf16* __restrict__ segb){
  int g  = (blockIdx.x*256 + threadIdx.x) >> 4;   // segment id, always < NRR
  int fl = threadIdx.x & 15;
  int o = off[g], c = cnt[g];
  float scale = 1.0f / fmaxf((float)c, 1.0f);
  f32x4 acc = {0.f, 0.f, 0.f, 0.f};
  for (int i = 0; i < c; ++i){
    int s = elist[o + i];
    bf16x4 v = *(const bf16x4*)(&xb[(size_t)s*64 + fl*4]);
    acc[0] += (float)v[0]; acc[1] += (float)v[1];
    acc[2] += (float)v[2]; acc[3] += (float)v[3];
  }
  bf16x4 r;
  r[0]=(__bf16)(acc[0]*scale); r[1]=(__bf16)(acc[1]*scale);
  r[2]=(__bf16)(acc[2]*scale); r[3]=(__bf16)(acc[3]*scale);
  *(bf16x4*)(&segb[(size_t)g*64 + fl*4]) = r;
}

// ---------------- fused dense + highway ----------------
// Block = 128 nodes (two 64-row halves), 4 waves, 16x16x32 bf16 MFMA.
// GEMM1: [128 x 320] @ W1^T -> sigmoid -> h ; GEMM2: [h|prev] @ W2^T -> highway.
#define W2P 136   // LDS pitch (bf16) for W2
#define HSP 72    // LDS pitch (bf16) for h staging

template<bool LAYER1>
__global__ __launch_bounds__(256)
void dense_kernel(const __bf16* __restrict__ segb,  // [N*R,64] bf16 means
                  const __bf16* __restrict__ xinb,  // [N,64] conv self input
                  const __bf16* __restrict__ prevb, // [N,64] highway prev
                  const __bf16* __restrict__ W1,    // [64][320]
                  const __bf16* __restrict__ W2,    // [128][128]
                  const float* __restrict__ bias1,  // [64]
                  const float* __restrict__ bias2,  // [128]
                  __bf16* __restrict__ hb,          // layer1: conv out (bf16)
                  __bf16* __restrict__ gb,          // layer1: highway out (bf16)
                  float* __restrict__ outp)         // layer2: final fp32
{
  __shared__ __bf16 w2s[128*W2P];
  __shared__ __bf16 hs[128*HSP];

  const int tid = threadIdx.x;
  #pragma unroll
  for (int i = 0; i < 8; ++i) {
    int idx = i*2048 + tid*8;
    int n = idx >> 7, k = idx & 127;
    *(bf16x8*)(&w2s[n*W2P + k]) = *(const bf16x8*)(&W2[idx]);
  }
  __syncthreads();

  const int lane = tid & 63;
  const int wv   = tid >> 6;
  const int mloc = lane & 15;   // A-row / B-col within 16-tile
  const int kg   = lane >> 4;   // k-group
  const int base = blockIdx.x * 128;

  int arow[2];
  arow[0] = min(base      + wv*16 + mloc, NN-1);
  arow[1] = min(base + 64 + wv*16 + mloc, NN-1);

  f32x4 acc1[2][4] = {};

  // GEMM1 part 1: K = 0..256 from segb (upd)
  #pragma unroll
  for (int kb = 0; kb < 256; kb += 32) {
    bf16x8 bf[4];
    #pragma unroll
    for (int j = 0; j < 4; ++j)
      bf[j] = *(const bf16x8*)(&W1[(j*16 + mloc)*320 + kb + kg*8]);
    #pragma unroll
    for (int h = 0; h < 2; ++h) {
      bf16x8 af = *(const bf16x8*)(&segb[(size_t)arow[h]*256 + kb + kg*8]);
      #pragma unroll
      for (int j = 0; j < 4; ++j)
        acc1[h][j] = __builtin_amdgcn_mfma_f32_16x16x32_bf16(af, bf[j], acc1[h][j], 0,0,0);
    }
  }
  // GEMM1 part 2: K = 256..320 from xinb (self loop)
  #pragma unroll
  for (int kb = 0; kb < 64; kb += 32) {
    bf16x8 bf[4];
    #pragma unroll
    for (int j = 0; j < 4; ++j)
      bf[j] = *(const bf16x8*)(&W1[(j*16 + mloc)*320 + 256 + kb + kg*8]);
    #pragma unroll
    for (int h = 0; h < 2; ++h) {
      bf16x8 af = *(const bf16x8*)(&xinb[(size_t)arow[h]*64 + kb + kg*8]);
      #pragma unroll
      for (int j = 0; j < 4; ++j)
        acc1[h][j] = __builtin_amdgcn_mfma_f32_16x16x32_bf16(af, bf[j], acc1[h][j], 0,0,0);
    }
  }

  // epilogue 1: h = sigmoid(acc + bias1); stage bf16 in LDS (wave-private rows)
  #pragma unroll
  for (int h = 0; h < 2; ++h) {
    #pragma unroll
    for (int j = 0; j < 4; ++j) {
      int col = j*16 + mloc;
      float b1 = bias1[col];
      #pragma unroll
      for (int r = 0; r < 4; ++r) {
        float hv = sigmoidf_(acc1[h][j][r] + b1);
        acc1[h][j][r] = hv;
        int trow = h*64 + wv*16 + kg*4 + r;
        hs[trow*HSP + col] = (__bf16)hv;
        if (LAYER1) {
          int grow = base + trow;
          if (grow < NN) hb[(size_t)grow*64 + col] = (__bf16)hv;
        }
      }
    }
  }

  f32x4 acc2[2][8] = {};
  // GEMM2 part 1: K = 0..64 -> c = h (from LDS)
  #pragma unroll
  for (int kb = 0; kb < 64; kb += 32) {
    bf16x8 af[2];
    #pragma unroll
    for (int h = 0; h < 2; ++h) {
      int trow = h*64 + wv*16 + mloc;
      af[h] = *(const bf16x8*)(&hs[trow*HSP + kb + kg*8]);
    }
    #pragma unroll
    for (int j = 0; j < 8; ++j) {
      bf16x8 bf = *(const bf16x8*)(&w2s[(j*16 + mloc)*W2P + kb + kg*8]);
      #pragma unroll
      for (int h = 0; h < 2; ++h)
        acc2[h][j] = __builtin_amdgcn_mfma_f32_16x16x32_bf16(af[h], bf, acc2[h][j], 0,0,0);
    }
  }
  // GEMM2 part 2: K = 64..128 -> c = prev (global bf16)
  #pragma unroll
  for (int kb = 0; kb < 64; kb += 32) {
    bf16x8 af[2];
    #pragma unroll
    for (int h = 0; h < 2; ++h)
      af[h] = *(const bf16x8*)(&prevb[(size_t)arow[h]*64 + kb + kg*8]);
    #pragma unroll
    for (int j = 0; j < 8; ++j) {
      bf16x8 bf = *(const bf16x8*)(&w2s[(j*16 + mloc)*W2P + 64 + kb + kg*8]);
      #pragma unroll
      for (int h = 0; h < 2; ++h)
        acc2[h][j] = __builtin_amdgcn_mfma_f32_16x16x32_bf16(af[h], bf, acc2[h][j], 0,0,0);
    }
  }

  // epilogue 2: pr = relu(.+pb), g = sigmoid(.+tb), out = g*pr + (1-g)*h
  #pragma unroll
  for (int h = 0; h < 2; ++h) {
    #pragma unroll
    for (int j = 0; j < 4; ++j) {
      int col = j*16 + mloc;
      float bp = bias2[col];
      float bt = bias2[64 + col];
      #pragma unroll
      for (int r = 0; r < 4; ++r) {
        float pr = fmaxf(acc2[h][j][r] + bp, 0.0f);
        float g  = sigmoidf_(acc2[h][j+4][r] + bt);
        float hv = acc1[h][j][r];
        float ov = g*pr + (1.0f - g)*hv;
        int grow = base + h*64 + wv*16 + kg*4 + r;
        if (grow < NN) {
          if (LAYER1) gb[(size_t)grow*64 + col] = (__bf16)ov;
          else        outp[(size_t)grow*64 + col] = ov;
        }
      }
    }
  }
}

extern "C" void kernel_launch(void* const* d_in, const int* in_sizes, int n_in,
                              void* d_out, int out_size, void* d_ws, size_t ws_size,
                              hipStream_t stream){
  const float* x    = (const float*)d_in[0];
  const int*   src  = (const int*)d_in[1];
  const int*   dst  = (const int*)d_in[2];
  const int*   rel  = (const int*)d_in[3];
  const float* c1w  = (const float*)d_in[4];
  const float* c1b  = (const float*)d_in[5];
  const float* c1ws = (const float*)d_in[6];
  const float* c1bs = (const float*)d_in[7];
  const float* h1pw = (const float*)d_in[8];
  const float* h1pb = (const float*)d_in[9];
  const float* h1tw = (const float*)d_in[10];
  const float* h1tb = (const float*)d_in[11];
  const float* c2w  = (const float*)d_in[12];
  const float* c2b  = (const float*)d_in[13];
  const float* c2ws = (const float*)d_in[14];
  const float* c2bs = (const float*)d_in[15];
  const float* h2pw = (const float*)d_in[16];
  const float* h2pb = (const float*)d_in[17];
  const float* h2tw = (const float*)d_in[18];
  const float* h2tb = (const float*)d_in[19];

  char* p = (char*)d_ws;
  __bf16* segb = (__bf16*)p;  p += (size_t)NRR*64*2;
  __bf16* xb   = (__bf16*)p;  p += (size_t)NN*64*2;
  __bf16* h1b  = (__bf16*)p;  p += (size_t)NN*64*2;
  __bf16* g1b  = (__bf16*)p;  p += (size_t)NN*64*2;
  int* cnt     = (int*)p;     p += (size_t)NRR*4;
  int* off     = (int*)p;     p += (size_t)NRR*4;
  int* cursor  = (int*)p;     p += (size_t)NRR*4;
  int* elist   = (int*)p;     p += (size_t)NE*4;
  int* bsum    = (int*)p;     p += 128*4;
  int* bbase   = (int*)p;     p += 128*4;
  __bf16* W1a  = (__bf16*)p;  p += 64*320*2;
  __bf16* W2a  = (__bf16*)p;  p += 128*128*2;
  __bf16* W1b  = (__bf16*)p;  p += 64*320*2;
  __bf16* W2b  = (__bf16*)p;  p += 128*128*2;
  float* B1a   = (float*)p;   p += 64*4;
  float* B2a   = (float*)p;   p += 128*4;
  float* B1b   = (float*)p;   p += 64*4;
  float* B2b   = (float*)p;   p += 128*4;

  float* out = (float*)d_out;

  // CSR build (shared by both layers)
  hipMemsetAsync(cnt, 0, (size_t)NRR*4, stream);
  count_kernel<<<(NE+255)/256, 256, 0, stream>>>(dst, rel, cnt);
  scan1_kernel<<<NB, 256, 0, stream>>>(cnt, bsum);
  scan2_kernel<<<1, 128, 0, stream>>>(bsum, bbase);
  scan3_kernel<<<NB, 256, 0, stream>>>(cnt, bbase, off, cursor);
  place_kernel<<<(NE+255)/256, 256, 0, stream>>>(src, dst, rel, cursor, elist);

  tobf16_kernel<<<(NN*64/8 + 255)/256, 256, 0, stream>>>(x, xb);
  prep_kernel<<<80, 256, 0, stream>>>(c1w, c1b, c1ws, c1bs, h1pw, h1pb, h1tw, h1tb,
                                      W1a, W2a, B1a, B2a);
  prep_kernel<<<80, 256, 0, stream>>>(c2w, c2b, c2ws, c2bs, h2pw, h2pb, h2tw, h2tb,
                                      W1b, W2b, B1b, B2b);

  // layer 1
  gather_kernel<<<NRR/16, 256, 0, stream>>>(xb, elist, off, cnt, segb);
  dense_kernel<true><<<(NN+127)/128, 256, 0, stream>>>(segb, xb, xb, W1a, W2a, B1a, B2a,
                                                       h1b, g1b, nullptr);
  // layer 2
  gather_kernel<<<NRR/16, 256, 0, stream>>>(g1b, elist, off, cnt, segb);
  dense_kernel<false><<<(NN+127)/128, 256, 0, stream>>>(segb, g1b, h1b, W1b, W2b, B1b, B2b,
                                                        nullptr, nullptr, out);
}